// Round 7
// baseline (345.595 us; speedup 1.0000x reference)
//
#include <hip/hip_runtime.h>
#include <hip/hip_fp16.h>
#include <math.h>

// GCN 2-layer forward on MI355X — round 16: MEASUREMENT ROUND.
//  Identical to round 15 except k_bfinal / k_agg1gemm2 / k_gather2f bodies
//  run TWICE (idempotent). This doubles their durations past the 59-µs
//  fill floor so they appear in the rocprof top-5 with full counters —
//  the ~225 µs backend has never been attributed. True cost = dur/2.
//  Next round reverts the rep loops and targets the largest contributor.

#define BSH  9                 // bucket = dst >> 9 (512 nodes/bucket)
#define BCAP 12288             // max edges per bucket (mean 8163, ~45 sigma)

typedef _Float16 half8 __attribute__((ext_vector_type(8)));
typedef _Float16 half4 __attribute__((ext_vector_type(4)));
typedef float floatx4 __attribute__((ext_vector_type(4)));

// -------- W1 -> fp16 B-fragment swizzle + bkt_cnt zero --------
static __global__ __launch_bounds__(256) void k_wfrag(const float* __restrict__ W1,
                                                      _Float16* __restrict__ w1f,
                                                      int* __restrict__ bkt_cnt) {
    int t = threadIdx.x;
    bkt_cnt[t] = 0;
    for (int idx = t; idx < 2048; idx += 256) {
        int kb = idx >> 8;
        int nt = (idx >> 6) & 3;
        int l  = idx & 63;
        int k0 = kb * 32 + ((l >> 4) << 3);
        int nn = nt * 16 + (l & 15);
        half8 b;
        #pragma unroll
        for (int j = 0; j < 8; ++j) b[j] = (_Float16)W1[(k0 + j) * 64 + nn];
        *(half8*)(w1f + (size_t)idx * 8) = b;
    }
}

// -------- fat kernel: blocks [0,nScat) = edge bucketing, rest = MFMA gemm1 --------
static __global__ __launch_bounds__(256) void k_fat(const float* __restrict__ x,
                                                    const _Float16* __restrict__ w1f,
                                                    _Float16* __restrict__ h1f,
                                                    const int* __restrict__ src,
                                                    const int* __restrict__ dst,
                                                    int* __restrict__ bkt_cnt,
                                                    int* __restrict__ epack,
                                                    int n, int e, int nScat) {
    __shared__ alignas(16) char smem[25600];
    int t = threadIdx.x;

    if ((int)blockIdx.x < nScat) {
        int*           sp    = (int*)smem;
        unsigned char* sbkt  = (unsigned char*)(smem + 16384);
        int*           cnt   = (int*)(smem + 20480);
        int*           loff  = (int*)(smem + 21504);
        int*           lcur  = (int*)(smem + 22528);
        int*           gbase = (int*)(smem + 23552);
        int*           sh    = (int*)(smem + 24576);
        int cb = blockIdx.x * 4096;
        int cc = min(4096, e - cb);

        cnt[t] = 0;
        __syncthreads();
        int ep[16]; unsigned char eb[16];
        int nv = 0;
        #pragma unroll
        for (int k = 0; k < 16; ++k) {
            int i = cb + k * 256 + t;
            if (i < e) {
                int s = src[i], d = dst[i];
                int b = d >> BSH;
                ep[nv] = ((d & 511) << 17) | s;
                eb[nv] = (unsigned char)b;
                atomicAdd(&cnt[b], 1);
                ++nv;
            }
        }
        __syncthreads();
        int v = cnt[t];
        sh[t] = v;
        __syncthreads();
        for (int o = 1; o < 256; o <<= 1) {
            int u = (t >= o) ? sh[t - o] : 0;
            __syncthreads();
            sh[t] += u;
            __syncthreads();
        }
        loff[t] = sh[t] - v;
        lcur[t] = sh[t] - v;
        if (v > 0) gbase[t] = t * BCAP + atomicAdd(&bkt_cnt[t], v);
        __syncthreads();
        for (int k = 0; k < nv; ++k) {
            int b = eb[k];
            int p = atomicAdd(&lcur[b], 1);
            sp[p] = ep[k];
            sbkt[p] = (unsigned char)b;
        }
        __syncthreads();
        for (int i = t; i < cc; i += 256) {
            int b = sbkt[i];
            epack[gbase[b] + (i - loff[b])] = sp[i];
        }
    } else {
        int l = t & 63;
        int w = t >> 6;
        int r0 = (blockIdx.x - nScat) * 128;

        const float* sg[2];
        #pragma unroll
        for (int mt = 0; mt < 2; ++mt) {
            int gr = r0 + w * 32 + mt * 16 + (l >> 2);
            gr = gr < n ? gr : n - 1;
            sg[mt] = x + (size_t)gr * 256 + (l & 3) * 8;
        }
        int sidx = (l & 15) * 4 + (l >> 4);

        floatx4 acc[2][4];
        #pragma unroll
        for (int mt = 0; mt < 2; ++mt)
            #pragma unroll
            for (int nt = 0; nt < 4; ++nt)
                acc[mt][nt] = (floatx4){0.f, 0.f, 0.f, 0.f};

        #pragma unroll
        for (int kb = 0; kb < 8; ++kb) {
            float4 stA[2][2];
            #pragma unroll
            for (int mt = 0; mt < 2; ++mt) {
                stA[mt][0] = *(const float4*)(sg[mt] + kb * 32);
                stA[mt][1] = *(const float4*)(sg[mt] + kb * 32 + 4);
            }
            half8 a[2];
            #pragma unroll
            for (int mt = 0; mt < 2; ++mt) {
                #pragma unroll
                for (int j = 0; j < 2; ++j) {
                    float f0 = __shfl(stA[mt][j].x, sidx);
                    float f1 = __shfl(stA[mt][j].y, sidx);
                    float f2 = __shfl(stA[mt][j].z, sidx);
                    float f3 = __shfl(stA[mt][j].w, sidx);
                    a[mt][j * 4 + 0] = (_Float16)f0;
                    a[mt][j * 4 + 1] = (_Float16)f1;
                    a[mt][j * 4 + 2] = (_Float16)f2;
                    a[mt][j * 4 + 3] = (_Float16)f3;
                }
            }
            #pragma unroll
            for (int nt = 0; nt < 4; ++nt) {
                half8 b = *(const half8*)(w1f + ((size_t)(kb * 4 + nt) * 64 + l) * 8);
                acc[0][nt] = __builtin_amdgcn_mfma_f32_16x16x32_f16(a[0], b, acc[0][nt], 0, 0, 0);
                acc[1][nt] = __builtin_amdgcn_mfma_f32_16x16x32_f16(a[1], b, acc[1][nt], 0, 0, 0);
            }
        }

        int quad = l >> 4;
        int col  = l & 15;
        int rb0  = r0 + w * 32;
        #pragma unroll
        for (int mt = 0; mt < 2; ++mt) {
            #pragma unroll
            for (int r = 0; r < 4; ++r) {
                int rr = rb0 + mt * 16 + quad * 4 + r;
                if (rr < n) {
                    _Float16* o = h1f + (size_t)rr * 64 + col;
                    #pragma unroll
                    for (int nt = 0; nt < 4; ++nt)
                        o[nt * 16] = (_Float16)acc[mt][nt][r];
                }
            }
        }
    }
}

// -------- per bucket: deg->dinv, LDS scan -> offs, fill csr_src (x2 rep) --------
static __global__ __launch_bounds__(512) void k_bfinal(const int* __restrict__ bkt_cnt,
                                                       const int* __restrict__ epack,
                                                       float* __restrict__ dinv,
                                                       int* __restrict__ offs,
                                                       int* __restrict__ csr_src, int n) {
    __shared__ int cnt[512], sh[512], lcur[512];
    int t = threadIdx.x;
    int base = blockIdx.x << BSH;
    int e0 = blockIdx.x * BCAP;
    int e1 = e0 + bkt_cnt[blockIdx.x];
    #pragma unroll 1
    for (int rep = 0; rep < 2; ++rep) {
        cnt[t] = 0;
        __syncthreads();
        for (int i = e0 + t; i < e1; i += 512) atomicAdd(&cnt[epack[i] >> 17], 1);
        __syncthreads();
        int v = cnt[t];
        if (base + t < n) dinv[base + t] = 1.0f / sqrtf((float)(v + 1));
        sh[t] = v;
        __syncthreads();
        for (int o = 1; o < 512; o <<= 1) {
            int u = (t >= o) ? sh[t - o] : 0;
            __syncthreads();
            sh[t] += u;
            __syncthreads();
        }
        int incl = sh[t];
        if (base + t < n) offs[base + t] = e0 + incl;
        lcur[t] = e0 + incl - v;
        __syncthreads();
        for (int i = e0 + t; i < e1; i += 512) {
            int p = epack[i];
            int d = p >> 17;
            int pos = atomicAdd(&lcur[d], 1);
            csr_src[pos] = p & 0x1FFFF;
        }
        __syncthreads();
    }
}

// -------- fused agg1 + gemm2: 8 lanes/node x 8 feats, 32 nodes/block (x2 rep) --------
static __global__ __launch_bounds__(256) void k_agg1gemm2(const int* __restrict__ offs,
                                                          const int* __restrict__ csr_src,
                                                          const float* __restrict__ dinv,
                                                          const uint4* __restrict__ h1q,
                                                          const float* __restrict__ b1,
                                                          const float* __restrict__ W2,
                                                          __half2* __restrict__ h2h, int n) {
    __shared__ float Wl[64 * 32];       // 8 KB
    __shared__ float aggL[32][65];      // padded
    int t = threadIdx.x;
    *(float4*)(Wl + t * 4)        = *(const float4*)(W2 + t * 4);
    *(float4*)(Wl + t * 4 + 1024) = *(const float4*)(W2 + t * 4 + 1024);

    int li = t & 7;
    int ni = t >> 3;
    int node  = blockIdx.x * 32 + ni;
    int nodeC = node < n ? node : n - 1;
    int start = (nodeC & 511) ? offs[nodeC - 1] : (nodeC >> BSH) * BCAP;
    int end   = offs[nodeC];
    float dd  = dinv[nodeC];

    #pragma unroll 1
    for (int rep = 0; rep < 2; ++rep) {
        float a[8];
        {
            uint4 su = h1q[(size_t)nodeC * 8 + li];
            const __half2* hp = (const __half2*)&su;
            #pragma unroll
            for (int q = 0; q < 4; ++q) {
                float2 f = __half22float2(hp[q]);
                a[2 * q] = dd * f.x; a[2 * q + 1] = dd * f.y;
            }
        }

        int j = start;
        for (; j + 7 < end; j += 8) {
            int sk[8];
            #pragma unroll
            for (int u = 0; u < 8; ++u) sk[u] = csr_src[j + u];
            float wq[8]; uint4 vv[8];
            #pragma unroll
            for (int u = 0; u < 8; ++u) {
                wq[u] = dinv[sk[u]];
                vv[u] = h1q[(size_t)sk[u] * 8 + li];
            }
            #pragma unroll
            for (int u = 0; u < 8; ++u) {
                const __half2* hp = (const __half2*)&vv[u];
                #pragma unroll
                for (int q = 0; q < 4; ++q) {
                    float2 f = __half22float2(hp[q]);
                    a[2 * q] += wq[u] * f.x; a[2 * q + 1] += wq[u] * f.y;
                }
            }
        }
        for (; j < end; ++j) {
            int s = csr_src[j];
            float wv = dinv[s];
            uint4 v = h1q[(size_t)s * 8 + li];
            const __half2* hp = (const __half2*)&v;
            #pragma unroll
            for (int q = 0; q < 4; ++q) {
                float2 f = __half22float2(hp[q]);
                a[2 * q] += wv * f.x; a[2 * q + 1] += wv * f.y;
            }
        }

        float4 bb0 = *(const float4*)(b1 + li * 8);
        float4 bb1 = *(const float4*)(b1 + li * 8 + 4);
        aggL[ni][li * 8 + 0] = fmaxf(dd * a[0] + bb0.x, 0.f);
        aggL[ni][li * 8 + 1] = fmaxf(dd * a[1] + bb0.y, 0.f);
        aggL[ni][li * 8 + 2] = fmaxf(dd * a[2] + bb0.z, 0.f);
        aggL[ni][li * 8 + 3] = fmaxf(dd * a[3] + bb0.w, 0.f);
        aggL[ni][li * 8 + 4] = fmaxf(dd * a[4] + bb1.x, 0.f);
        aggL[ni][li * 8 + 5] = fmaxf(dd * a[5] + bb1.y, 0.f);
        aggL[ni][li * 8 + 6] = fmaxf(dd * a[6] + bb1.z, 0.f);
        aggL[ni][li * 8 + 7] = fmaxf(dd * a[7] + bb1.w, 0.f);
        __syncthreads();

        if (node < n) {
            float s0 = 0.f, s1 = 0.f, s2 = 0.f, s3 = 0.f;
            #pragma unroll
            for (int k = 0; k < 64; ++k) {
                float av = aggL[ni][k];
                float4 wv = *(const float4*)(Wl + k * 32 + li * 4);
                s0 += av * wv.x; s1 += av * wv.y; s2 += av * wv.z; s3 += av * wv.w;
            }
            h2h[(size_t)node * 16 + li * 2]     = __float22half2_rn(make_float2(s0, s1));
            h2h[(size_t)node * 16 + li * 2 + 1] = __float22half2_rn(make_float2(s2, s3));
        }
        __syncthreads();
    }
}

// -------- fused agg2 + final projection: 4 lanes/node x 8 feats (x2 rep) --------
static __global__ __launch_bounds__(256) void k_gather2f(const int* __restrict__ offs,
                                                         const int* __restrict__ csr_src,
                                                         const float* __restrict__ dinv,
                                                         const uint4* __restrict__ h2q,
                                                         const float* __restrict__ b2,
                                                         const float* __restrict__ Wlin,
                                                         const float* __restrict__ blin,
                                                         float* __restrict__ out, int n) {
    int g    = blockIdx.x * 256 + threadIdx.x;
    int node = g >> 2;
    if (node >= n) return;
    int li = g & 3;
    int start = (node & 511) ? offs[node - 1] : (node >> BSH) * BCAP;
    int end   = offs[node];
    float dd  = dinv[node];

    #pragma unroll 1
    for (int rep = 0; rep < 2; ++rep) {
        float a[8];
        {
            uint4 su = h2q[(size_t)node * 4 + li];
            const __half2* hp = (const __half2*)&su;
            #pragma unroll
            for (int q = 0; q < 4; ++q) {
                float2 f = __half22float2(hp[q]);
                a[2 * q] = dd * f.x; a[2 * q + 1] = dd * f.y;
            }
        }

        int j = start;
        for (; j + 7 < end; j += 8) {
            int sk[8];
            #pragma unroll
            for (int u = 0; u < 8; ++u) sk[u] = csr_src[j + u];
            float wq[8]; uint4 vv[8];
            #pragma unroll
            for (int u = 0; u < 8; ++u) {
                wq[u] = dinv[sk[u]];
                vv[u] = h2q[(size_t)sk[u] * 4 + li];
            }
            #pragma unroll
            for (int u = 0; u < 8; ++u) {
                const __half2* hp = (const __half2*)&vv[u];
                #pragma unroll
                for (int q = 0; q < 4; ++q) {
                    float2 f = __half22float2(hp[q]);
                    a[2 * q] += wq[u] * f.x; a[2 * q + 1] += wq[u] * f.y;
                }
            }
        }
        for (; j < end; ++j) {
            int s = csr_src[j];
            float wv = dinv[s];
            uint4 v = h2q[(size_t)s * 4 + li];
            const __half2* hp = (const __half2*)&v;
            #pragma unroll
            for (int q = 0; q < 4; ++q) {
                float2 f = __half22float2(hp[q]);
                a[2 * q] += wv * f.x; a[2 * q + 1] += wv * f.y;
            }
        }

        float4 bb0 = *(const float4*)(b2 + li * 8);
        float4 bb1 = *(const float4*)(b2 + li * 8 + 4);
        float4 wl0 = *(const float4*)(Wlin + li * 8);
        float4 wl1 = *(const float4*)(Wlin + li * 8 + 4);
        float val = fmaxf(dd * a[0] + bb0.x, 0.f) * wl0.x +
                    fmaxf(dd * a[1] + bb0.y, 0.f) * wl0.y +
                    fmaxf(dd * a[2] + bb0.z, 0.f) * wl0.z +
                    fmaxf(dd * a[3] + bb0.w, 0.f) * wl0.w +
                    fmaxf(dd * a[4] + bb1.x, 0.f) * wl1.x +
                    fmaxf(dd * a[5] + bb1.y, 0.f) * wl1.y +
                    fmaxf(dd * a[6] + bb1.z, 0.f) * wl1.z +
                    fmaxf(dd * a[7] + bb1.w, 0.f) * wl1.w;
        val += __shfl_xor(val, 2);
        val += __shfl_xor(val, 1);
        if (li == 0) out[node] = val + blin[0];
    }
}

extern "C" void kernel_launch(void* const* d_in, const int* in_sizes, int n_in,
                              void* d_out, int out_size, void* d_ws, size_t ws_size,
                              hipStream_t stream) {
    const float* x    = (const float*)d_in[0];
    const int*   ei   = (const int*)d_in[1];
    const float* W1   = (const float*)d_in[2];
    const float* b1   = (const float*)d_in[3];
    const float* W2   = (const float*)d_in[4];
    const float* b2   = (const float*)d_in[5];
    const float* Wlin = (const float*)d_in[6];
    const float* blin = (const float*)d_in[7];
    float* out = (float*)d_out;

    const int n = in_sizes[0] / 256;   // 100000
    const int e = in_sizes[1] / 2;     // 1600000
    const int* src = ei;
    const int* dst = ei + e;
    const int nbkt  = (n + (1 << BSH) - 1) >> BSH;   // 196
    const int nScat = (e + 4095) / 4096;             // 391
    const int nGemm = (n + 127) / 128;               // 782

    char* wp = (char*)d_ws;
    _Float16* h1f = (_Float16*)wp;
    uint4*    h1q = (uint4*)wp;       wp += (size_t)n * 32 * 4;
    __half2*  h2h = (__half2*)wp;
    uint4*    h2q = (uint4*)wp;       wp += (size_t)n * 32 * 2;
    float*    dinv = (float*)wp;      wp += (size_t)n * 4;
    int*      offs = (int*)wp;        wp += (size_t)n * 4;
    int*      csr_src = (int*)wp;     wp += (size_t)nbkt * BCAP * 4;
    int*      epack = (int*)wp;       wp += (size_t)nbkt * BCAP * 4;
    int*      bkt_cnt = (int*)wp;     wp += 256 * 4;
    _Float16* w1f = (_Float16*)wp;    // 32 KB

    dim3 B(256);
    k_wfrag <<<1, B, 0, stream>>>(W1, w1f, bkt_cnt);
    k_fat   <<<nScat + nGemm, B, 0, stream>>>(x, w1f, h1f, src, dst, bkt_cnt, epack, n, e, nScat);
    k_bfinal<<<nbkt, 512, 0, stream>>>(bkt_cnt, epack, dinv, offs, csr_src, n);
    k_agg1gemm2<<<(n + 31) / 32, B, 0, stream>>>(offs, csr_src, dinv, h1q, b1, W2, h2h, n);
    k_gather2f <<<(n * 4 + 255) / 256, B, 0, stream>>>(offs, csr_src, dinv, h2q,
                                                       b2, Wlin, blin, out, n);
}

// Round 9
// 275.895 us; speedup vs baseline: 1.2526x; 1.2526x over previous
//
#include <hip/hip_runtime.h>
#include <hip/hip_fp16.h>
#include <math.h>

// GCN 2-layer forward on MI355X — round 18 (= round 17 resubmitted; the
// previous bench died to an infra "container failed twice" error, kernel
// never ran):
//  - NORM FACTORIZATION: h1 rows pre-scaled by dinv[node] in k_bfinal's
//    tail (thread t owns node base+t); h2 rows pre-scaled by dd in
//    k_agg1gemm2's epilogue (free). Both agg kernels lose the per-edge
//    dinv[s] gather -> 33% fewer VMEM issues in the latency-bound inner
//    loops, shorter dep chains.
//  - k_fat / k_wfrag unchanged (r15 form).

#define BSH  9                 // bucket = dst >> 9 (512 nodes/bucket)
#define BCAP 12288             // max edges per bucket (mean 8163, ~45 sigma)

typedef _Float16 half8 __attribute__((ext_vector_type(8)));
typedef _Float16 half4 __attribute__((ext_vector_type(4)));
typedef float floatx4 __attribute__((ext_vector_type(4)));

// -------- W1 -> fp16 B-fragment swizzle + bkt_cnt zero --------
static __global__ __launch_bounds__(256) void k_wfrag(const float* __restrict__ W1,
                                                      _Float16* __restrict__ w1f,
                                                      int* __restrict__ bkt_cnt) {
    int t = threadIdx.x;
    bkt_cnt[t] = 0;
    for (int idx = t; idx < 2048; idx += 256) {
        int kb = idx >> 8;
        int nt = (idx >> 6) & 3;
        int l  = idx & 63;
        int k0 = kb * 32 + ((l >> 4) << 3);
        int nn = nt * 16 + (l & 15);
        half8 b;
        #pragma unroll
        for (int j = 0; j < 8; ++j) b[j] = (_Float16)W1[(k0 + j) * 64 + nn];
        *(half8*)(w1f + (size_t)idx * 8) = b;
    }
}

// -------- fat kernel: blocks [0,nScat) = edge bucketing, rest = MFMA gemm1 --------
static __global__ __launch_bounds__(256) void k_fat(const float* __restrict__ x,
                                                    const _Float16* __restrict__ w1f,
                                                    _Float16* __restrict__ h1f,
                                                    const int* __restrict__ src,
                                                    const int* __restrict__ dst,
                                                    int* __restrict__ bkt_cnt,
                                                    int* __restrict__ epack,
                                                    int n, int e, int nScat) {
    __shared__ alignas(16) char smem[25600];
    int t = threadIdx.x;

    if ((int)blockIdx.x < nScat) {
        int*           sp    = (int*)smem;
        unsigned char* sbkt  = (unsigned char*)(smem + 16384);
        int*           cnt   = (int*)(smem + 20480);
        int*           loff  = (int*)(smem + 21504);
        int*           lcur  = (int*)(smem + 22528);
        int*           gbase = (int*)(smem + 23552);
        int*           sh    = (int*)(smem + 24576);
        int cb = blockIdx.x * 4096;
        int cc = min(4096, e - cb);

        cnt[t] = 0;
        __syncthreads();
        int ep[16]; unsigned char eb[16];
        int nv = 0;
        #pragma unroll
        for (int k = 0; k < 16; ++k) {
            int i = cb + k * 256 + t;
            if (i < e) {
                int s = src[i], d = dst[i];
                int b = d >> BSH;
                ep[nv] = ((d & 511) << 17) | s;
                eb[nv] = (unsigned char)b;
                atomicAdd(&cnt[b], 1);
                ++nv;
            }
        }
        __syncthreads();
        int v = cnt[t];
        sh[t] = v;
        __syncthreads();
        for (int o = 1; o < 256; o <<= 1) {
            int u = (t >= o) ? sh[t - o] : 0;
            __syncthreads();
            sh[t] += u;
            __syncthreads();
        }
        loff[t] = sh[t] - v;
        lcur[t] = sh[t] - v;
        if (v > 0) gbase[t] = t * BCAP + atomicAdd(&bkt_cnt[t], v);
        __syncthreads();
        for (int k = 0; k < nv; ++k) {
            int b = eb[k];
            int p = atomicAdd(&lcur[b], 1);
            sp[p] = ep[k];
            sbkt[p] = (unsigned char)b;
        }
        __syncthreads();
        for (int i = t; i < cc; i += 256) {
            int b = sbkt[i];
            epack[gbase[b] + (i - loff[b])] = sp[i];
        }
    } else {
        int l = t & 63;
        int w = t >> 6;
        int r0 = (blockIdx.x - nScat) * 128;

        const float* sg[2];
        #pragma unroll
        for (int mt = 0; mt < 2; ++mt) {
            int gr = r0 + w * 32 + mt * 16 + (l >> 2);
            gr = gr < n ? gr : n - 1;
            sg[mt] = x + (size_t)gr * 256 + (l & 3) * 8;
        }
        int sidx = (l & 15) * 4 + (l >> 4);

        floatx4 acc[2][4];
        #pragma unroll
        for (int mt = 0; mt < 2; ++mt)
            #pragma unroll
            for (int nt = 0; nt < 4; ++nt)
                acc[mt][nt] = (floatx4){0.f, 0.f, 0.f, 0.f};

        #pragma unroll
        for (int kb = 0; kb < 8; ++kb) {
            float4 stA[2][2];
            #pragma unroll
            for (int mt = 0; mt < 2; ++mt) {
                stA[mt][0] = *(const float4*)(sg[mt] + kb * 32);
                stA[mt][1] = *(const float4*)(sg[mt] + kb * 32 + 4);
            }
            half8 a[2];
            #pragma unroll
            for (int mt = 0; mt < 2; ++mt) {
                #pragma unroll
                for (int j = 0; j < 2; ++j) {
                    float f0 = __shfl(stA[mt][j].x, sidx);
                    float f1 = __shfl(stA[mt][j].y, sidx);
                    float f2 = __shfl(stA[mt][j].z, sidx);
                    float f3 = __shfl(stA[mt][j].w, sidx);
                    a[mt][j * 4 + 0] = (_Float16)f0;
                    a[mt][j * 4 + 1] = (_Float16)f1;
                    a[mt][j * 4 + 2] = (_Float16)f2;
                    a[mt][j * 4 + 3] = (_Float16)f3;
                }
            }
            #pragma unroll
            for (int nt = 0; nt < 4; ++nt) {
                half8 b = *(const half8*)(w1f + ((size_t)(kb * 4 + nt) * 64 + l) * 8);
                acc[0][nt] = __builtin_amdgcn_mfma_f32_16x16x32_f16(a[0], b, acc[0][nt], 0, 0, 0);
                acc[1][nt] = __builtin_amdgcn_mfma_f32_16x16x32_f16(a[1], b, acc[1][nt], 0, 0, 0);
            }
        }

        int quad = l >> 4;
        int col  = l & 15;
        int rb0  = r0 + w * 32;
        #pragma unroll
        for (int mt = 0; mt < 2; ++mt) {
            #pragma unroll
            for (int r = 0; r < 4; ++r) {
                int rr = rb0 + mt * 16 + quad * 4 + r;
                if (rr < n) {
                    _Float16* o = h1f + (size_t)rr * 64 + col;
                    #pragma unroll
                    for (int nt = 0; nt < 4; ++nt)
                        o[nt * 16] = (_Float16)acc[mt][nt][r];
                }
            }
        }
    }
}

// -------- per bucket: deg->dinv, scan->offs, scatter csr, PRESCALE h1 --------
static __global__ __launch_bounds__(512) void k_bfinal(const int* __restrict__ bkt_cnt,
                                                       const int* __restrict__ epack,
                                                       float* __restrict__ dinv,
                                                       int* __restrict__ offs,
                                                       int* __restrict__ csr_src,
                                                       uint4* __restrict__ h1q, int n) {
    __shared__ int cnt[512], sh[512], lcur[512];
    int t = threadIdx.x;
    int base = blockIdx.x << BSH;
    int e0 = blockIdx.x * BCAP;
    int e1 = e0 + bkt_cnt[blockIdx.x];
    cnt[t] = 0;
    __syncthreads();
    for (int i = e0 + t; i < e1; i += 512) atomicAdd(&cnt[epack[i] >> 17], 1);
    __syncthreads();
    int v = cnt[t];
    float ddl = 1.0f / sqrtf((float)(v + 1));
    if (base + t < n) dinv[base + t] = ddl;
    sh[t] = v;
    __syncthreads();
    for (int o = 1; o < 512; o <<= 1) {
        int u = (t >= o) ? sh[t - o] : 0;
        __syncthreads();
        sh[t] += u;
        __syncthreads();
    }
    int incl = sh[t];
    if (base + t < n) offs[base + t] = e0 + incl;
    lcur[t] = e0 + incl - v;
    __syncthreads();
    for (int i = e0 + t; i < e1; i += 512) {
        int p = epack[i];
        int d = p >> 17;
        int pos = atomicAdd(&lcur[d], 1);
        csr_src[pos] = p & 0x1FFFF;
    }
    // prescale own node's h1 row by dinv (no sync needed: own-row only)
    if (base + t < n) {
        uint4* row = h1q + (size_t)(base + t) * 8;
        #pragma unroll
        for (int k = 0; k < 8; ++k) {
            uint4 vv = row[k];
            __half2* hp = (__half2*)&vv;
            #pragma unroll
            for (int q = 0; q < 4; ++q) {
                float2 f = __half22float2(hp[q]);
                hp[q] = __float22half2_rn(make_float2(f.x * ddl, f.y * ddl));
            }
            row[k] = vv;
        }
    }
}

// -------- fused agg1 + gemm2: 8 lanes/node x 8 feats (h1 pre-scaled) --------
static __global__ __launch_bounds__(256) void k_agg1gemm2(const int* __restrict__ offs,
                                                          const int* __restrict__ csr_src,
                                                          const float* __restrict__ dinv,
                                                          const uint4* __restrict__ h1q,
                                                          const float* __restrict__ b1,
                                                          const float* __restrict__ W2,
                                                          __half2* __restrict__ h2h, int n) {
    __shared__ float Wl[64 * 32];       // 8 KB
    __shared__ float aggL[32][65];      // padded
    int t = threadIdx.x;
    *(float4*)(Wl + t * 4)        = *(const float4*)(W2 + t * 4);
    *(float4*)(Wl + t * 4 + 1024) = *(const float4*)(W2 + t * 4 + 1024);

    int li = t & 7;
    int ni = t >> 3;
    int node  = blockIdx.x * 32 + ni;
    int nodeC = node < n ? node : n - 1;
    int start = (nodeC & 511) ? offs[nodeC - 1] : (nodeC >> BSH) * BCAP;
    int end   = offs[nodeC];
    float dd  = dinv[nodeC];

    float a[8];
    {
        // self-loop: h1q already dinv-scaled
        uint4 su = h1q[(size_t)nodeC * 8 + li];
        const __half2* hp = (const __half2*)&su;
        #pragma unroll
        for (int q = 0; q < 4; ++q) {
            float2 f = __half22float2(hp[q]);
            a[2 * q] = f.x; a[2 * q + 1] = f.y;
        }
    }

    int j = start;
    for (; j + 7 < end; j += 8) {
        int sk[8];
        #pragma unroll
        for (int u = 0; u < 8; ++u) sk[u] = csr_src[j + u];
        uint4 vv[8];
        #pragma unroll
        for (int u = 0; u < 8; ++u) vv[u] = h1q[(size_t)sk[u] * 8 + li];
        #pragma unroll
        for (int u = 0; u < 8; ++u) {
            const __half2* hp = (const __half2*)&vv[u];
            #pragma unroll
            for (int q = 0; q < 4; ++q) {
                float2 f = __half22float2(hp[q]);
                a[2 * q] += f.x; a[2 * q + 1] += f.y;
            }
        }
    }
    for (; j < end; ++j) {
        int s = csr_src[j];
        uint4 v = h1q[(size_t)s * 8 + li];
        const __half2* hp = (const __half2*)&v;
        #pragma unroll
        for (int q = 0; q < 4; ++q) {
            float2 f = __half22float2(hp[q]);
            a[2 * q] += f.x; a[2 * q + 1] += f.y;
        }
    }

    float4 bb0 = *(const float4*)(b1 + li * 8);
    float4 bb1 = *(const float4*)(b1 + li * 8 + 4);
    aggL[ni][li * 8 + 0] = fmaxf(dd * a[0] + bb0.x, 0.f);
    aggL[ni][li * 8 + 1] = fmaxf(dd * a[1] + bb0.y, 0.f);
    aggL[ni][li * 8 + 2] = fmaxf(dd * a[2] + bb0.z, 0.f);
    aggL[ni][li * 8 + 3] = fmaxf(dd * a[3] + bb0.w, 0.f);
    aggL[ni][li * 8 + 4] = fmaxf(dd * a[4] + bb1.x, 0.f);
    aggL[ni][li * 8 + 5] = fmaxf(dd * a[5] + bb1.y, 0.f);
    aggL[ni][li * 8 + 6] = fmaxf(dd * a[6] + bb1.z, 0.f);
    aggL[ni][li * 8 + 7] = fmaxf(dd * a[7] + bb1.w, 0.f);
    __syncthreads();

    if (node < n) {
        float s0 = 0.f, s1 = 0.f, s2 = 0.f, s3 = 0.f;
        #pragma unroll
        for (int k = 0; k < 64; ++k) {
            float av = aggL[ni][k];
            float4 wv = *(const float4*)(Wl + k * 32 + li * 4);
            s0 += av * wv.x; s1 += av * wv.y; s2 += av * wv.z; s3 += av * wv.w;
        }
        // store h2 PRE-SCALED by dinv[node] -> g2f needs no per-edge weight
        h2h[(size_t)node * 16 + li * 2]     = __float22half2_rn(make_float2(s0 * dd, s1 * dd));
        h2h[(size_t)node * 16 + li * 2 + 1] = __float22half2_rn(make_float2(s2 * dd, s3 * dd));
    }
}

// -------- fused agg2 + final projection: 4 lanes/node x 8 feats (h2 pre-scaled) --------
static __global__ __launch_bounds__(256) void k_gather2f(const int* __restrict__ offs,
                                                         const int* __restrict__ csr_src,
                                                         const float* __restrict__ dinv,
                                                         const uint4* __restrict__ h2q,
                                                         const float* __restrict__ b2,
                                                         const float* __restrict__ Wlin,
                                                         const float* __restrict__ blin,
                                                         float* __restrict__ out, int n) {
    int g    = blockIdx.x * 256 + threadIdx.x;
    int node = g >> 2;
    if (node >= n) return;
    int li = g & 3;
    int start = (node & 511) ? offs[node - 1] : (node >> BSH) * BCAP;
    int end   = offs[node];
    float dd  = dinv[node];

    float a[8];
    {
        uint4 su = h2q[(size_t)node * 4 + li];
        const __half2* hp = (const __half2*)&su;
        #pragma unroll
        for (int q = 0; q < 4; ++q) {
            float2 f = __half22float2(hp[q]);
            a[2 * q] = f.x; a[2 * q + 1] = f.y;
        }
    }

    int j = start;
    for (; j + 7 < end; j += 8) {
        int sk[8];
        #pragma unroll
        for (int u = 0; u < 8; ++u) sk[u] = csr_src[j + u];
        uint4 vv[8];
        #pragma unroll
        for (int u = 0; u < 8; ++u) vv[u] = h2q[(size_t)sk[u] * 4 + li];
        #pragma unroll
        for (int u = 0; u < 8; ++u) {
            const __half2* hp = (const __half2*)&vv[u];
            #pragma unroll
            for (int q = 0; q < 4; ++q) {
                float2 f = __half22float2(hp[q]);
                a[2 * q] += f.x; a[2 * q + 1] += f.y;
            }
        }
    }
    for (; j < end; ++j) {
        int s = csr_src[j];
        uint4 v = h2q[(size_t)s * 4 + li];
        const __half2* hp = (const __half2*)&v;
        #pragma unroll
        for (int q = 0; q < 4; ++q) {
            float2 f = __half22float2(hp[q]);
            a[2 * q] += f.x; a[2 * q + 1] += f.y;
        }
    }

    float4 bb0 = *(const float4*)(b2 + li * 8);
    float4 bb1 = *(const float4*)(b2 + li * 8 + 4);
    float4 wl0 = *(const float4*)(Wlin + li * 8);
    float4 wl1 = *(const float4*)(Wlin + li * 8 + 4);
    float val = fmaxf(dd * a[0] + bb0.x, 0.f) * wl0.x +
                fmaxf(dd * a[1] + bb0.y, 0.f) * wl0.y +
                fmaxf(dd * a[2] + bb0.z, 0.f) * wl0.z +
                fmaxf(dd * a[3] + bb0.w, 0.f) * wl0.w +
                fmaxf(dd * a[4] + bb1.x, 0.f) * wl1.x +
                fmaxf(dd * a[5] + bb1.y, 0.f) * wl1.y +
                fmaxf(dd * a[6] + bb1.z, 0.f) * wl1.z +
                fmaxf(dd * a[7] + bb1.w, 0.f) * wl1.w;
    val += __shfl_xor(val, 2);
    val += __shfl_xor(val, 1);
    if (li == 0) out[node] = val + blin[0];
}

extern "C" void kernel_launch(void* const* d_in, const int* in_sizes, int n_in,
                              void* d_out, int out_size, void* d_ws, size_t ws_size,
                              hipStream_t stream) {
    const float* x    = (const float*)d_in[0];
    const int*   ei   = (const int*)d_in[1];
    const float* W1   = (const float*)d_in[2];
    const float* b1   = (const float*)d_in[3];
    const float* W2   = (const float*)d_in[4];
    const float* b2   = (const float*)d_in[5];
    const float* Wlin = (const float*)d_in[6];
    const float* blin = (const float*)d_in[7];
    float* out = (float*)d_out;

    const int n = in_sizes[0] / 256;   // 100000
    const int e = in_sizes[1] / 2;     // 1600000
    const int* src = ei;
    const int* dst = ei + e;
    const int nbkt  = (n + (1 << BSH) - 1) >> BSH;   // 196
    const int nScat = (e + 4095) / 4096;             // 391
    const int nGemm = (n + 127) / 128;               // 782

    char* wp = (char*)d_ws;
    _Float16* h1f = (_Float16*)wp;
    uint4*    h1q = (uint4*)wp;       wp += (size_t)n * 32 * 4;
    __half2*  h2h = (__half2*)wp;
    uint4*    h2q = (uint4*)wp;       wp += (size_t)n * 32 * 2;
    float*    dinv = (float*)wp;      wp += (size_t)n * 4;
    int*      offs = (int*)wp;        wp += (size_t)n * 4;
    int*      csr_src = (int*)wp;     wp += (size_t)nbkt * BCAP * 4;
    int*      epack = (int*)wp;       wp += (size_t)nbkt * BCAP * 4;
    int*      bkt_cnt = (int*)wp;     wp += 256 * 4;
    _Float16* w1f = (_Float16*)wp;    // 32 KB

    dim3 B(256);
    k_wfrag <<<1, B, 0, stream>>>(W1, w1f, bkt_cnt);
    k_fat   <<<nScat + nGemm, B, 0, stream>>>(x, w1f, h1f, src, dst, bkt_cnt, epack, n, e, nScat);
    k_bfinal<<<nbkt, 512, 0, stream>>>(bkt_cnt, epack, dinv, offs, csr_src, h1q, n);
    k_agg1gemm2<<<(n + 31) / 32, B, 0, stream>>>(offs, csr_src, dinv, h1q, b1, W2, h2h, n);
    k_gather2f <<<(n * 4 + 255) / 256, B, 0, stream>>>(offs, csr_src, dinv, h2q,
                                                       b2, Wlin, blin, out, n);
}